// Round 18
// baseline (338.128 us; speedup 1.0000x reference)
//
#include <hip/hip_runtime.h>
#include <hip/hip_bf16.h>

typedef short bf16x8 __attribute__((ext_vector_type(8)));
typedef short bf16x4 __attribute__((ext_vector_type(4)));
typedef float f32x4  __attribute__((ext_vector_type(4)));

static constexpr int Bb   = 128;
static constexpr int Cin  = 32;
static constexpr int Nn   = 325;
static constexpr int Tt   = 24;
static constexpr int Cout = 64;
static constexpr int NKS  = 11;    // K steps of 32 (352)
static constexpr int WP   = 336;   // padded w rows per (ep,ks) plane
static constexpr int NWT  = 21;    // w-tiles of 16
static constexpr size_t XTB_ELEMS = (size_t)Bb * NKS * (Tt * Cin) * 32;
static constexpr size_t STP_ELEMS = (size_t)3 * NKS * WP * 32;   // no identity
static constexpr size_t WB_ELEMS  = (size_t)Cout * 128;

__device__ __forceinline__ void gld16(const void* g, void* l) {
    __builtin_amdgcn_global_load_lds(
        (const __attribute__((address_space(1))) void*)g,
        (__attribute__((address_space(3))) void*)l, 16, 0, 0);
}
__device__ __forceinline__ short bfb(float f) {
    __hip_bfloat16 h = __float2bfloat16(f);
    return *reinterpret_cast<short*>(&h);
}

// ---------- P1: fused build: stpb[ep][ks][w(336)][vi] (ep=e-1) + Wb -------
__global__ void build_tabs(const float* __restrict__ sup,
                           const float* __restrict__ W,
                           __hip_bfloat16* __restrict__ stpb,
                           __hip_bfloat16* __restrict__ Wb) {
    int idx = blockIdx.x * 256 + threadIdx.x;
    int total = 3 * NKS * WP * 32;
    if (idx < total) {
        int ep = idx / (NKS * WP * 32);
        int r  = idx % (NKS * WP * 32);
        int ks = r / (WP * 32);
        int r2 = r % (WP * 32);
        int w  = r2 / 32;
        int vi = r2 % 32;
        int v  = ks * 32 + vi;
        float val = 0.f;
        if (v < Nn && w < Nn)
            val = sup[((size_t)ep * Nn + v) * Nn + w];
        stpb[idx] = __float2bfloat16(val);
    } else {
        int wi = idx - total;
        if (wi < Cout * 128) Wb[wi] = __float2bfloat16(W[wi]);
    }
}

// ---------- P2: x -> xTb[b][ks][ct=t*32+c][vi(32)]; XCD-affine: b/16 ------
__global__ void transpose_x(const float* __restrict__ x,
                            __hip_bfloat16* __restrict__ xTb) {
    __shared__ __hip_bfloat16 ls[Cin * 32 * 28];   // [c][vi][28]
    int xcd = blockIdx.x & 7;
    int idx = blockIdx.x >> 3;        // [0,176): 16 b x 11 ks
    int b   = xcd * 16 + idx / NKS;
    int ks  = idx % NKS;
    int tid = threadIdx.x;
    for (int i = 0; i < 24; ++i) {
        int f4 = i * 256 + tid;
        int c  = f4 / 192;
        int rm = f4 % 192;
        int vi = rm / 6;
        int t0 = (rm % 6) * 4;
        int v  = ks * 32 + vi;
        float4 val = make_float4(0.f, 0.f, 0.f, 0.f);
        if (v < Nn)
            val = *(const float4*)(x + (((size_t)(b * Cin + c) * Nn + v) * Tt + t0));
        bf16x4 pk = { bfb(val.x), bfb(val.y), bfb(val.z), bfb(val.w) };
        *(bf16x4*)&ls[(c * 32 + vi) * 28 + t0] = pk;
    }
    __syncthreads();
    for (int j = 0; j < 12; ++j) {
        int o    = j * 256 + tid;
        int row  = o >> 2;
        int slot = o & 3;
        int t = row >> 5, c = row & 31;
        union { short us[8]; bf16x8 v8; } pk;
#pragma unroll
        for (int q = 0; q < 8; ++q) {
            __hip_bfloat16 h = ls[(c * 32 + slot * 8 + q) * 28 + t];
            pk.us[q] = *reinterpret_cast<short*>(&h);
        }
        *(bf16x8*)((char*)xTb + ((size_t)(b * NKS + ks) * 768 + row) * 64 + slot * 16) = pk.v8;
    }
}

// ---------- M: 384thr/6waves; LDS 78848B -> 2 blocks/CU = 3 waves/SIMD ----
__global__ __launch_bounds__(384, 3) void graphconv_main(
    const __hip_bfloat16* __restrict__ xTb,
    const __hip_bfloat16* __restrict__ stpb,
    const __hip_bfloat16* __restrict__ Wb,
    const float* __restrict__ bias,
    float* __restrict__ out) {
    // ring: 2 x 6 x 4 KB = 49152 B; Ss: 29 slabs x 1 KB = 29696 B. = 78848 B
    __shared__ alignas(16) char smem[49152 + 29696];
    char*  ring = smem;
    char*  Ss   = smem + 49152;
    float* Os   = (float*)smem;    // 32 o x 16 w x 13 = 26624 B (overlay)

    // bijective XCD swizzle: 5376 = 8 * 672; th innermost, wt next
    int bid = blockIdx.x;
    int lg  = (bid & 7) * 672 + (bid >> 3);
    int b   = lg / 42;
    int r   = lg % 42;
    int wt  = r >> 1, th = r & 1;
    int w0  = wt * 16;

    int tid = threadIdx.x, wid = tid >> 6, lane = tid & 63;
    int cl = lane & 15, kg = lane >> 4;

    int srow  = lane >> 2;                             // row 0..15
    int sslot = ((lane & 3) ^ ((lane >> 3) & 3)) << 4; // R5-verified pair
    const int asw = (kg ^ ((cl >> 1) & 3)) << 4;

    const char* xslab = (const char*)xTb + (size_t)b * NKS * 768 * 64;
    const char* xsrc  = xslab + (size_t)(th * 384 + wid * 64 + srow) * 64 + sslot;
    char*       xdst  = ring + wid * 4096 + lane * 16;

    // ---- prologue: Ss gld16 (slabs 0..28), afk reg loads (29..32) --------
    for (int i = wid; i < 29; i += 6) {
        gld16((const char*)stpb + ((size_t)i * WP + w0 + srow) * 64 + sslot,
              Ss + i * 1024 + lane * 16);
    }
    bf16x8 afk[4];   // slabs 29..32 = (ep=2, ks=7..10), unswizzled reg path
#pragma unroll
    for (int i = 0; i < 4; ++i)
        afk[i] = *(const bf16x8*)((const char*)stpb +
                     ((size_t)(29 + i) * WP + w0 + cl) * 64 + kg * 16);
#pragma unroll
    for (int i = 0; i < 4; ++i)
        asm volatile("" : "+v"(afk[i]));   // force materialization + wait
    asm volatile("s_waitcnt vmcnt(0)" ::: "memory");   // Ss + afk drained
    __builtin_amdgcn_sched_barrier(0);
    __builtin_amdgcn_s_barrier();          // Ss visible to block

    // ring staging AFTER the barrier: loop vmcnt counts only ring gld16s
#pragma unroll
    for (int s = 0; s < 2; ++s)
#pragma unroll
        for (int q = 0; q < 4; ++q)
            gld16(xsrc + (size_t)s * 49152 + q * 1024,
                  xdst + s * 24576 + q * 1024);

    // ---- GEMM1 K-loop: barrier-free; steady vmcnt(4) ----
    f32x4 acc1[3][4] = {};
#pragma unroll
    for (int ks = 0; ks < NKS; ++ks) {
        if (ks < 10) { asm volatile("s_waitcnt vmcnt(4)" ::: "memory"); }
        else         { asm volatile("s_waitcnt vmcnt(0)" ::: "memory"); }
        __builtin_amdgcn_sched_barrier(0);
        const int bsel = (ks & 1) * 24576;
        bf16x8 xf[4];
#pragma unroll
        for (int j = 0; j < 4; ++j)
            xf[j] = *(const bf16x8*)(ring + bsel + wid * 4096 + j * 1024 +
                                     cl * 64 + asw);
        asm volatile("s_waitcnt lgkmcnt(0)" ::: "memory");
        __builtin_amdgcn_sched_barrier(0);
        if (ks < 9) {   // restage this buffer for ks+2 (xf safely in regs)
#pragma unroll
            for (int q = 0; q < 4; ++q)
                gld16(xsrc + (size_t)(ks + 2) * 49152 + q * 1024,
                      xdst + bsel + q * 1024);
        }
        bf16x8 af[3];
#pragma unroll
        for (int ep = 0; ep < 3; ++ep) {
            const int slab = ep * NKS + ks;
            af[ep] = (slab < 29)
                ? *(const bf16x8*)(Ss + slab * 1024 + cl * 64 + asw)
                : afk[slab - 29];
        }
#pragma unroll
        for (int ep = 0; ep < 3; ++ep)
#pragma unroll
            for (int j = 0; j < 4; ++j)
                acc1[ep][j] = __builtin_amdgcn_mfma_f32_16x16x32_bf16(
                    xf[j], af[ep], acc1[ep][j], 0, 0, 0);
    }

    // ---- identity GEMM2 B-frags: direct bf16 loads from xTb --------------
    // pbx[j][r] = X[ct][v=w0+cl]: slab wt>>1, vi=16*(wt&1)+cl,
    // ct = (th*12 + wid*2 + (j>>1))*32 + (j&1)*16 + kg*4 + r.
    const char* xid = xslab + (size_t)(wt >> 1) * 49152 +
                      (size_t)(16 * (wt & 1) + cl) * 2;
    bf16x4 pbx[4];
#pragma unroll
    for (int j = 0; j < 4; ++j) {
        const char* rp = xid + (size_t)((th * 12 + wid * 2 + (j >> 1)) * 32 +
                                        (j & 1) * 16 + kg * 4) * 64;
        bf16x4 p = { *(const short*)(rp),       *(const short*)(rp + 64),
                     *(const short*)(rp + 128), *(const short*)(rp + 192) };
        pbx[j] = p;
    }

    // ---- GEMM2 from registers: kappa = es*2 + (j&1), tj = j>>1 ----
    f32x4 acc2[4][2] = {};
#pragma unroll
    for (int kappa = 0; kappa < 8; ++kappa) {
        const int es = kappa >> 1, half = kappa & 1;
        bf16x4 wf[4];
#pragma unroll
        for (int mt = 0; mt < 4; ++mt)
            wf[mt] = *(const bf16x4*)((const char*)Wb + (mt * 16 + cl) * 256 +
                                      kappa * 32 + kg * 8);
#pragma unroll
        for (int tj = 0; tj < 2; ++tj) {
            const int j = tj * 2 + half;
            bf16x4 pb;
            if (es == 0) {
                pb = pbx[j];
            } else {
                f32x4 y = acc1[es - 1][j];
                bf16x4 t4 = { bfb(y[0]), bfb(y[1]), bfb(y[2]), bfb(y[3]) };
                pb = t4;
            }
#pragma unroll
            for (int mt = 0; mt < 4; ++mt)
                acc2[mt][tj] = __builtin_amdgcn_mfma_f32_16x16x16bf16_1k(
                    wf[mt], pb, acc2[mt][tj], 0, 0, 0);
        }
    }

    // ---- epilogue: Os overlays ring; 2 passes of 32 o; 48 B pieces ----
    __builtin_amdgcn_s_barrier();          // all ring/Ss reads done
#pragma unroll
    for (int p = 0; p < 2; ++p) {
        if (p) {
            asm volatile("s_waitcnt lgkmcnt(0)" ::: "memory");
            __builtin_amdgcn_s_barrier();  // pass-0 reads done
        }
#pragma unroll
        for (int mh = 0; mh < 2; ++mh) {
            const int mt = p * 2 + mh;
#pragma unroll
            for (int tj = 0; tj < 2; ++tj) {
                const int t = wid * 2 + tj;
#pragma unroll
                for (int r2_ = 0; r2_ < 4; ++r2_)
                    Os[(mh * 16 + kg * 4 + r2_) * 208 + cl * 13 + t] =
                        acc2[mt][tj][r2_];
            }
        }
        asm volatile("s_waitcnt lgkmcnt(0)" ::: "memory");
        __builtin_amdgcn_s_barrier();
        for (int pair = tid; pair < 512; pair += 384) {
            const int o2 = pair >> 4, w = pair & 15;
            const int wg = w0 + w;
            if (wg < Nn) {
                const int o = p * 32 + o2;
                const float bv = bias[o];
                float f[12];
#pragma unroll
                for (int q = 0; q < 12; ++q)
                    f[q] = Os[o2 * 208 + w * 13 + q] + bv;
                float* op = out + ((size_t)(b * Cout + o) * Nn + wg) * Tt + th * 12;
#pragma unroll
                for (int q3 = 0; q3 < 3; ++q3)
                    *(float4*)(op + q3 * 4) = make_float4(
                        f[q3 * 4], f[q3 * 4 + 1], f[q3 * 4 + 2], f[q3 * 4 + 3]);
            }
        }
    }
}

extern "C" void kernel_launch(void* const* d_in, const int* in_sizes, int n_in,
                              void* d_out, int out_size, void* d_ws, size_t ws_size,
                              hipStream_t stream) {
    const float* x    = (const float*)d_in[0];
    const float* sup  = (const float*)d_in[1];
    const float* W    = (const float*)d_in[2];
    const float* bias = (const float*)d_in[3];
    float* out = (float*)d_out;

    __hip_bfloat16* xTb  = (__hip_bfloat16*)d_ws;
    __hip_bfloat16* stpb = xTb + XTB_ELEMS;
    __hip_bfloat16* Wb   = stpb + STP_ELEMS;

    int build_total = (int)(STP_ELEMS + WB_ELEMS);
    build_tabs<<<(build_total + 255) / 256, 256, 0, stream>>>(sup, W, stpb, Wb);
    transpose_x<<<Bb * NKS, 256, 0, stream>>>(x, xTb);
    graphconv_main<<<Bb * NWT * 2, 384, 0, stream>>>(xTb, stpb, Wb, bias, out);
}

// Round 19
// 331.038 us; speedup vs baseline: 1.0214x; 1.0214x over previous
//
#include <hip/hip_runtime.h>
#include <hip/hip_bf16.h>

typedef short bf16x8 __attribute__((ext_vector_type(8)));
typedef short bf16x4 __attribute__((ext_vector_type(4)));
typedef float f32x4  __attribute__((ext_vector_type(4)));

static constexpr int Bb   = 128;
static constexpr int Cin  = 32;
static constexpr int Nn   = 325;
static constexpr int Tt   = 24;
static constexpr int Cout = 64;
static constexpr int NKS  = 11;    // K steps of 32 (352)
static constexpr int WP   = 336;   // padded w rows per (ep,ks) plane
static constexpr int NWT  = 21;    // w-tiles of 16
static constexpr size_t XTB_ELEMS = (size_t)Bb * NKS * (Tt * Cin) * 32;
static constexpr size_t STP_ELEMS = (size_t)3 * NKS * WP * 32;   // no identity
static constexpr size_t WB_ELEMS  = (size_t)Cout * 128;

__device__ __forceinline__ void gld16(const void* g, void* l) {
    __builtin_amdgcn_global_load_lds(
        (const __attribute__((address_space(1))) void*)g,
        (__attribute__((address_space(3))) void*)l, 16, 0, 0);
}
__device__ __forceinline__ short bfb(float f) {
    __hip_bfloat16 h = __float2bfloat16(f);
    return *reinterpret_cast<short*>(&h);
}

// ---------- P1: fused build: stpb[ep][ks][w(336)][vi] (ep=e-1) + Wb -------
__global__ void build_tabs(const float* __restrict__ sup,
                           const float* __restrict__ W,
                           __hip_bfloat16* __restrict__ stpb,
                           __hip_bfloat16* __restrict__ Wb) {
    int idx = blockIdx.x * 256 + threadIdx.x;
    int total = 3 * NKS * WP * 32;
    if (idx < total) {
        int ep = idx / (NKS * WP * 32);
        int r  = idx % (NKS * WP * 32);
        int ks = r / (WP * 32);
        int r2 = r % (WP * 32);
        int w  = r2 / 32;
        int vi = r2 % 32;
        int v  = ks * 32 + vi;
        float val = 0.f;
        if (v < Nn && w < Nn)
            val = sup[((size_t)ep * Nn + v) * Nn + w];
        stpb[idx] = __float2bfloat16(val);
    } else {
        int wi = idx - total;
        if (wi < Cout * 128) Wb[wi] = __float2bfloat16(W[wi]);
    }
}

// ---------- P2: x -> xTb[b][ks][ct=t*32+c][vi(32)]; XCD-affine: b/16 ------
__global__ void transpose_x(const float* __restrict__ x,
                            __hip_bfloat16* __restrict__ xTb) {
    __shared__ __hip_bfloat16 ls[Cin * 32 * 28];   // [c][vi][28]
    int xcd = blockIdx.x & 7;
    int idx = blockIdx.x >> 3;        // [0,176): 16 b x 11 ks
    int b   = xcd * 16 + idx / NKS;
    int ks  = idx % NKS;
    int tid = threadIdx.x;
    for (int i = 0; i < 24; ++i) {
        int f4 = i * 256 + tid;
        int c  = f4 / 192;
        int rm = f4 % 192;
        int vi = rm / 6;
        int t0 = (rm % 6) * 4;
        int v  = ks * 32 + vi;
        float4 val = make_float4(0.f, 0.f, 0.f, 0.f);
        if (v < Nn)
            val = *(const float4*)(x + (((size_t)(b * Cin + c) * Nn + v) * Tt + t0));
        bf16x4 pk = { bfb(val.x), bfb(val.y), bfb(val.z), bfb(val.w) };
        *(bf16x4*)&ls[(c * 32 + vi) * 28 + t0] = pk;
    }
    __syncthreads();
    for (int j = 0; j < 12; ++j) {
        int o    = j * 256 + tid;
        int row  = o >> 2;
        int slot = o & 3;
        int t = row >> 5, c = row & 31;
        union { short us[8]; bf16x8 v8; } pk;
#pragma unroll
        for (int q = 0; q < 8; ++q) {
            __hip_bfloat16 h = ls[(c * 32 + slot * 8 + q) * 28 + t];
            pk.us[q] = *reinterpret_cast<short*>(&h);
        }
        *(bf16x8*)((char*)xTb + ((size_t)(b * NKS + ks) * 768 + row) * 64 + slot * 16) = pk.v8;
    }
}

// ---------- M: block=(b,wt), 768thr/12waves -> 3 waves/SIMD, 1 block/CU ---
__global__ __launch_bounds__(768, 3) void graphconv_main(
    const __hip_bfloat16* __restrict__ xTb,
    const __hip_bfloat16* __restrict__ stpb,
    const __hip_bfloat16* __restrict__ Wb,
    const float* __restrict__ bias,
    float* __restrict__ out) {
    // ring: 2 x 12 x 4 KB = 98304 B; Ss: 29 x 1 KB = 29696 B. total 128000 B
    __shared__ alignas(16) char smem[98304 + 29696];
    char*  ring = smem;
    char*  Ss   = smem + 98304;
    float* Os   = (float*)smem;    // 32 o x 16 w x 25 = 51200 B (overlay)

    // bijective XCD swizzle: 2688 = 8 * 336; wt innermost (X L2 reuse x21)
    int bid = blockIdx.x;
    int lg  = (bid & 7) * 336 + (bid >> 3);
    int b   = lg / NWT;
    int wt  = lg % NWT;
    int w0  = wt * 16;

    int tid = threadIdx.x, wid = tid >> 6, lane = tid & 63;
    int cl = lane & 15, kg = lane >> 4;

    int srow  = lane >> 2;                             // row 0..15
    int sslot = ((lane & 3) ^ ((lane >> 3) & 3)) << 4; // R5-verified pair
    const int asw = (kg ^ ((cl >> 1) & 3)) << 4;

    const char* xslab = (const char*)xTb + (size_t)b * NKS * 768 * 64;
    const char* xsrc  = xslab + (size_t)(wid * 64 + srow) * 64 + sslot;
    char*       xdst  = ring + wid * 4096 + lane * 16;

    // ---- prologue: Ss gld16 (slabs 0..28), afk reg loads (29..32) --------
    for (int i = wid; i < 29; i += 12) {
        gld16((const char*)stpb + ((size_t)i * WP + w0 + srow) * 64 + sslot,
              Ss + i * 1024 + lane * 16);
    }
    bf16x8 afk[4];   // slabs 29..32 = (ep=2, ks=7..10), unswizzled reg path
#pragma unroll
    for (int i = 0; i < 4; ++i)
        afk[i] = *(const bf16x8*)((const char*)stpb +
                     ((size_t)(29 + i) * WP + w0 + cl) * 64 + kg * 16);
#pragma unroll
    for (int i = 0; i < 4; ++i)
        asm volatile("" : "+v"(afk[i]));   // force materialization
    asm volatile("s_waitcnt vmcnt(0)" ::: "memory");   // Ss + afk drained
    __builtin_amdgcn_sched_barrier(0);
    __builtin_amdgcn_s_barrier();          // Ss visible to block

    // ring staging AFTER the barrier: loop vmcnt counts only ring gld16s
#pragma unroll
    for (int s = 0; s < 2; ++s)
#pragma unroll
        for (int q = 0; q < 4; ++q)
            gld16(xsrc + (size_t)s * 49152 + q * 1024,
                  xdst + s * 49152 + q * 1024);

    // ---- GEMM1 K-loop: barrier-free; steady vmcnt(4) ----
    f32x4 acc1[3][4] = {};
#pragma unroll
    for (int ks = 0; ks < NKS; ++ks) {
        if (ks < 10) { asm volatile("s_waitcnt vmcnt(4)" ::: "memory"); }
        else         { asm volatile("s_waitcnt vmcnt(0)" ::: "memory"); }
        __builtin_amdgcn_sched_barrier(0);
        const int bsel = (ks & 1) * 49152;
        bf16x8 xf[4];
#pragma unroll
        for (int j = 0; j < 4; ++j)
            xf[j] = *(const bf16x8*)(ring + bsel + wid * 4096 + j * 1024 +
                                     cl * 64 + asw);
        asm volatile("s_waitcnt lgkmcnt(0)" ::: "memory");
        __builtin_amdgcn_sched_barrier(0);
        if (ks < 9) {   // restage this buffer for ks+2 (xf safely in regs)
#pragma unroll
            for (int q = 0; q < 4; ++q)
                gld16(xsrc + (size_t)(ks + 2) * 49152 + q * 1024,
                      xdst + bsel + q * 1024);
        }
        bf16x8 af[3];
#pragma unroll
        for (int ep = 0; ep < 3; ++ep) {
            const int slab = ep * NKS + ks;
            af[ep] = (slab < 29)
                ? *(const bf16x8*)(Ss + slab * 1024 + cl * 64 + asw)
                : afk[slab - 29];
        }
#pragma unroll
        for (int ep = 0; ep < 3; ++ep)
#pragma unroll
            for (int j = 0; j < 4; ++j)
                acc1[ep][j] = __builtin_amdgcn_mfma_f32_16x16x32_bf16(
                    xf[j], af[ep], acc1[ep][j], 0, 0, 0);
    }

    // ---- identity GEMM2 B-frags: direct bf16 loads from xTb --------------
    // pbx[j][r] = X[ct][v=w0+cl]: slab wt>>1, vi=16*(wt&1)+cl,
    // ct = (wid*2 + (j>>1))*32 + (j&1)*16 + kg*4 + r.
    const char* xid = xslab + (size_t)(wt >> 1) * 49152 +
                      (size_t)(16 * (wt & 1) + cl) * 2;
    bf16x4 pbx[4];
#pragma unroll
    for (int j = 0; j < 4; ++j) {
        const char* rp = xid + (size_t)((wid * 2 + (j >> 1)) * 32 +
                                        (j & 1) * 16 + kg * 4) * 64;
        bf16x4 p = { *(const short*)(rp),       *(const short*)(rp + 64),
                     *(const short*)(rp + 128), *(const short*)(rp + 192) };
        pbx[j] = p;
    }

    // ---- GEMM2 from registers: kappa = es*2 + (j&1), tj = j>>1 ----
    f32x4 acc2[4][2] = {};
#pragma unroll
    for (int kappa = 0; kappa < 8; ++kappa) {
        const int es = kappa >> 1, half = kappa & 1;
        bf16x4 wf[4];
#pragma unroll
        for (int mt = 0; mt < 4; ++mt)
            wf[mt] = *(const bf16x4*)((const char*)Wb + (mt * 16 + cl) * 256 +
                                      kappa * 32 + kg * 8);
#pragma unroll
        for (int tj = 0; tj < 2; ++tj) {
            const int j = tj * 2 + half;
            bf16x4 pb;
            if (es == 0) {
                pb = pbx[j];
            } else {
                f32x4 y = acc1[es - 1][j];
                bf16x4 t4 = { bfb(y[0]), bfb(y[1]), bfb(y[2]), bfb(y[3]) };
                pb = t4;
            }
#pragma unroll
            for (int mt = 0; mt < 4; ++mt)
                acc2[mt][tj] = __builtin_amdgcn_mfma_f32_16x16x16bf16_1k(
                    wf[mt], pb, acc2[mt][tj], 0, 0, 0);
        }
    }

    // ---- epilogue: Os overlays ring; 2 passes of 32 o; full 96B rows ----
    __builtin_amdgcn_s_barrier();          // all ring/Ss reads done
#pragma unroll
    for (int p = 0; p < 2; ++p) {
        if (p) {
            asm volatile("s_waitcnt lgkmcnt(0)" ::: "memory");
            __builtin_amdgcn_s_barrier();  // pass-0 reads done
        }
#pragma unroll
        for (int mh = 0; mh < 2; ++mh) {
            const int mt = p * 2 + mh;
#pragma unroll
            for (int tj = 0; tj < 2; ++tj) {
                const int t = wid * 2 + tj;
#pragma unroll
                for (int r2_ = 0; r2_ < 4; ++r2_)
                    Os[(mh * 16 + kg * 4 + r2_) * 400 + cl * 25 + t] =
                        acc2[mt][tj][r2_];
            }
        }
        asm volatile("s_waitcnt lgkmcnt(0)" ::: "memory");
        __builtin_amdgcn_s_barrier();
        if (tid < 512) {
            const int o2 = tid >> 4, w = tid & 15;
            const int wg = w0 + w;
            if (wg < Nn) {
                const int o = p * 32 + o2;
                const float bv = bias[o];
                float f[24];
#pragma unroll
                for (int t = 0; t < 24; ++t)
                    f[t] = Os[o2 * 400 + w * 25 + t] + bv;
                float* op = out + ((size_t)(b * Cout + o) * Nn + wg) * Tt;
#pragma unroll
                for (int q3 = 0; q3 < 6; ++q3)
                    *(float4*)(op + q3 * 4) = make_float4(
                        f[q3 * 4], f[q3 * 4 + 1], f[q3 * 4 + 2], f[q3 * 4 + 3]);
            }
        }
    }
}

extern "C" void kernel_launch(void* const* d_in, const int* in_sizes, int n_in,
                              void* d_out, int out_size, void* d_ws, size_t ws_size,
                              hipStream_t stream) {
    const float* x    = (const float*)d_in[0];
    const float* sup  = (const float*)d_in[1];
    const float* W    = (const float*)d_in[2];
    const float* bias = (const float*)d_in[3];
    float* out = (float*)d_out;

    __hip_bfloat16* xTb  = (__hip_bfloat16*)d_ws;
    __hip_bfloat16* stpb = xTb + XTB_ELEMS;
    __hip_bfloat16* Wb   = stpb + STP_ELEMS;

    int build_total = (int)(STP_ELEMS + WB_ELEMS);
    build_tabs<<<(build_total + 255) / 256, 256, 0, stream>>>(sup, W, stpb, Wb);
    transpose_x<<<Bb * NKS, 256, 0, stream>>>(x, xTb);
    graphconv_main<<<Bb * NWT, 768, 0, stream>>>(xTb, stpb, Wb, bias, out);
}

// Round 20
// 283.531 us; speedup vs baseline: 1.1926x; 1.1676x over previous
//
#include <hip/hip_runtime.h>
#include <hip/hip_bf16.h>

typedef short bf16x8 __attribute__((ext_vector_type(8)));
typedef short bf16x4 __attribute__((ext_vector_type(4)));
typedef float f32x4  __attribute__((ext_vector_type(4)));

static constexpr int Bb   = 128;
static constexpr int Cin  = 32;
static constexpr int Nn   = 325;
static constexpr int Tt   = 24;
static constexpr int Cout = 64;
static constexpr int NKS  = 11;    // K steps of 32 (352)
static constexpr int WP   = 336;   // padded w rows per (ep,ks) plane
static constexpr int NWT  = 21;    // w-tiles of 16
static constexpr size_t XTB_ELEMS = (size_t)Bb * NKS * (Tt * Cin) * 32;
static constexpr size_t STP_ELEMS = (size_t)3 * NKS * WP * 32;   // no identity
static constexpr size_t WB_ELEMS  = (size_t)Cout * 128;

__device__ __forceinline__ void gld16(const void* g, void* l) {
    __builtin_amdgcn_global_load_lds(
        (const __attribute__((address_space(1))) void*)g,
        (__attribute__((address_space(3))) void*)l, 16, 0, 0);
}
__device__ __forceinline__ short bfb(float f) {
    __hip_bfloat16 h = __float2bfloat16(f);
    return *reinterpret_cast<short*>(&h);
}

// ---------- P1: fused build: stpb[ep][ks][w(336)][vi] (ep=e-1) + Wb -------
__global__ void build_tabs(const float* __restrict__ sup,
                           const float* __restrict__ W,
                           __hip_bfloat16* __restrict__ stpb,
                           __hip_bfloat16* __restrict__ Wb) {
    int idx = blockIdx.x * 256 + threadIdx.x;
    int total = 3 * NKS * WP * 32;
    if (idx < total) {
        int ep = idx / (NKS * WP * 32);
        int r  = idx % (NKS * WP * 32);
        int ks = r / (WP * 32);
        int r2 = r % (WP * 32);
        int w  = r2 / 32;
        int vi = r2 % 32;
        int v  = ks * 32 + vi;
        float val = 0.f;
        if (v < Nn && w < Nn)
            val = sup[((size_t)ep * Nn + v) * Nn + w];
        stpb[idx] = __float2bfloat16(val);
    } else {
        int wi = idx - total;
        if (wi < Cout * 128) Wb[wi] = __float2bfloat16(W[wi]);
    }
}

// ---------- P2: x -> xTb[b][ks][ct=t*32+c][vi(32)]; XCD-affine: b/16 ------
__global__ void transpose_x(const float* __restrict__ x,
                            __hip_bfloat16* __restrict__ xTb) {
    __shared__ __hip_bfloat16 ls[Cin * 32 * 28];   // [c][vi][28]
    int xcd = blockIdx.x & 7;
    int idx = blockIdx.x >> 3;        // [0,176): 16 b x 11 ks
    int b   = xcd * 16 + idx / NKS;
    int ks  = idx % NKS;
    int tid = threadIdx.x;
    for (int i = 0; i < 24; ++i) {
        int f4 = i * 256 + tid;
        int c  = f4 / 192;
        int rm = f4 % 192;
        int vi = rm / 6;
        int t0 = (rm % 6) * 4;
        int v  = ks * 32 + vi;
        float4 val = make_float4(0.f, 0.f, 0.f, 0.f);
        if (v < Nn)
            val = *(const float4*)(x + (((size_t)(b * Cin + c) * Nn + v) * Tt + t0));
        bf16x4 pk = { bfb(val.x), bfb(val.y), bfb(val.z), bfb(val.w) };
        *(bf16x4*)&ls[(c * 32 + vi) * 28 + t0] = pk;
    }
    __syncthreads();
    for (int j = 0; j < 12; ++j) {
        int o    = j * 256 + tid;
        int row  = o >> 2;
        int slot = o & 3;
        int t = row >> 5, c = row & 31;
        union { short us[8]; bf16x8 v8; } pk;
#pragma unroll
        for (int q = 0; q < 8; ++q) {
            __hip_bfloat16 h = ls[(c * 32 + slot * 8 + q) * 28 + t];
            pk.us[q] = *reinterpret_cast<short*>(&h);
        }
        *(bf16x8*)((char*)xTb + ((size_t)(b * NKS + ks) * 768 + row) * 64 + slot * 16) = pk.v8;
    }
}

// ---------- M: block=(b,wt) 512thr/8waves; identity synthesized -----------
// K-loop: zero barriers, counted vmcnt(6); 18 MFMA/iter (3 e-planes) + 6
// identity MFMAs at the single K-step ks == wt>>1 (in-register B-frag).
__global__ __launch_bounds__(512, 1) void graphconv_main(
    const __hip_bfloat16* __restrict__ xTb,
    const __hip_bfloat16* __restrict__ stpb,
    const __hip_bfloat16* __restrict__ Wb,
    const float* __restrict__ bias,
    float* __restrict__ out) {
    // ring: 2 x 8 x 6 KB = 98304 B; Ss: 33 KB. Os overlays ring.
    __shared__ alignas(16) char smem[98304 + 33792];
    char*  ring = smem;
    char*  Ss   = smem + 98304;
    float* Os   = (float*)smem;    // 32 o x (16 w x 25) = 51200 B

    // bijective XCD swizzle: 2688 = 8 * 336; wt innermost (X L2 reuse x21)
    int bid = blockIdx.x;
    int lg  = (bid & 7) * 336 + (bid >> 3);
    int b   = lg / NWT;
    int wt  = lg % NWT;
    int w0  = wt * 16;

    int tid = threadIdx.x, wid = tid >> 6, lane = tid & 63;
    int cl = lane & 15, kg = lane >> 4;

    int srow  = lane >> 2;                             // row 0..15
    int sslot = ((lane & 3) ^ ((lane >> 3) & 3)) << 4; // R5-verified pair
    const int asw = (kg ^ ((cl >> 1) & 3)) << 4;

    const char* xslab = (const char*)xTb + (size_t)b * NKS * 768 * 64;
    const char* xsrc  = xslab + (size_t)(wid * 96 + srow) * 64 + sslot;
    char*       xdst  = ring + wid * 6144 + lane * 16;

    // ---- prologue: S' 33 slabs (<=5 gld16/wave), then X ks=0,1 ----
    for (int i = wid; i < 33; i += 8) {
        gld16((const char*)stpb + ((size_t)i * WP + w0 + srow) * 64 + sslot,
              Ss + i * 1024 + lane * 16);
    }
#pragma unroll
    for (int s = 0; s < 2; ++s)
#pragma unroll
        for (int q = 0; q < 6; ++q)
            gld16(xsrc + (size_t)s * 49152 + q * 1024,
                  xdst + s * 49152 + q * 1024);

    // identity B-frag (R13-verified): hot at ks==wt>>1, k = 16*(wt&1)+cl
    bf16x8 idf;
    {
        short hot = (kg == 2 * (wt & 1) + (cl >> 3)) ? (short)0x3F80 : (short)0;
        bf16x8 z = { 0, 0, 0, 0, 0, 0, 0, 0 };
#pragma unroll
        for (int i = 0; i < 8; ++i)
            z[i] = (i == (cl & 7)) ? hot : (short)0;
        idf = z;
    }
    const int id_ks = wt >> 1;

    asm volatile("s_waitcnt vmcnt(12)" ::: "memory");   // own S' drained
    __builtin_amdgcn_sched_barrier(0);
    __builtin_amdgcn_s_barrier();                       // S' visible, no drain

    // ---- GEMM1 K-loop: barrier-free, counted vmcnt ----
    f32x4 acc1[3][6] = {};
    f32x4 aid[6]     = {};
#pragma unroll
    for (int ks = 0; ks < NKS; ++ks) {
        if (ks < 10) { asm volatile("s_waitcnt vmcnt(6)" ::: "memory"); }
        else         { asm volatile("s_waitcnt vmcnt(0)" ::: "memory"); }
        __builtin_amdgcn_sched_barrier(0);
        const int bsel = (ks & 1) * 49152;
        bf16x8 xf[6];
#pragma unroll
        for (int j = 0; j < 6; ++j)
            xf[j] = *(const bf16x8*)(ring + bsel + wid * 6144 + j * 1024 +
                                     cl * 64 + asw);
        asm volatile("s_waitcnt lgkmcnt(0)" ::: "memory");
        __builtin_amdgcn_sched_barrier(0);
        if (ks < 9) {   // restage this buffer for ks+2 (xf in regs)
#pragma unroll
            for (int q = 0; q < 6; ++q)
                gld16(xsrc + (size_t)(ks + 2) * 49152 + q * 1024,
                      xdst + bsel + q * 1024);
        }
        bf16x8 af[3];
#pragma unroll
        for (int ep = 0; ep < 3; ++ep)
            af[ep] = *(const bf16x8*)(Ss + (ep * NKS + ks) * 1024 + cl * 64 + asw);
#pragma unroll
        for (int ep = 0; ep < 3; ++ep)
#pragma unroll
            for (int j = 0; j < 6; ++j)
                acc1[ep][j] = __builtin_amdgcn_mfma_f32_16x16x32_bf16(
                    xf[j], af[ep], acc1[ep][j], 0, 0, 0);
        if (ks == id_ks) {   // block-uniform branch; 6 MFMAs once per block
#pragma unroll
            for (int j = 0; j < 6; ++j)
                aid[j] = __builtin_amdgcn_mfma_f32_16x16x32_bf16(
                    xf[j], idf, aid[j], 0, 0, 0);
        }
    }

    // ---- GEMM2 from registers: kappa = es*2 + (j&1), tj = j>>1 ----
    // es==0 -> identity slice (aid), else acc1[es-1].
    f32x4 acc2[4][3] = {};
#pragma unroll
    for (int kappa = 0; kappa < 8; ++kappa) {
        const int es = kappa >> 1, half = kappa & 1;
        bf16x4 wf[4];
#pragma unroll
        for (int mt = 0; mt < 4; ++mt)
            wf[mt] = *(const bf16x4*)((const char*)Wb + (mt * 16 + cl) * 256 +
                                      kappa * 32 + kg * 8);
#pragma unroll
        for (int tj = 0; tj < 3; ++tj) {
            const int j = tj * 2 + half;
            f32x4 y = (es == 0) ? aid[j] : acc1[es - 1][j];
            bf16x4 pb = { bfb(y[0]), bfb(y[1]), bfb(y[2]), bfb(y[3]) };
#pragma unroll
            for (int mt = 0; mt < 4; ++mt)
                acc2[mt][tj] = __builtin_amdgcn_mfma_f32_16x16x16bf16_1k(
                    wf[mt], pb, acc2[mt][tj], 0, 0, 0);
        }
    }

    // ---- epilogue: Os overlays ring; 2 passes of 32 o; full 96B rows ----
    __builtin_amdgcn_s_barrier();          // all ring/Ss reads done
#pragma unroll
    for (int p = 0; p < 2; ++p) {
        if (p) {
            asm volatile("s_waitcnt lgkmcnt(0)" ::: "memory");
            __builtin_amdgcn_s_barrier();  // pass-0 reads done
        }
#pragma unroll
        for (int mh = 0; mh < 2; ++mh) {
            const int mt = p * 2 + mh;
#pragma unroll
            for (int tj = 0; tj < 3; ++tj) {
                const int t = wid * 3 + tj;
#pragma unroll
                for (int r2_ = 0; r2_ < 4; ++r2_)
                    Os[(mh * 16 + kg * 4 + r2_) * 400 + cl * 25 + t] =
                        acc2[mt][tj][r2_];
            }
        }
        asm volatile("s_waitcnt lgkmcnt(0)" ::: "memory");
        __builtin_amdgcn_s_barrier();
        const int o2 = tid >> 4, w = tid & 15;   // 512 threads = 32 o x 16 w
        const int wg = w0 + w;
        if (wg < Nn) {
            const int o = p * 32 + o2;
            const float bv = bias[o];
            float f[24];
#pragma unroll
            for (int t = 0; t < 24; ++t)
                f[t] = Os[o2 * 400 + w * 25 + t] + bv;
            float* op = out + ((size_t)(b * Cout + o) * Nn + wg) * Tt;
#pragma unroll
            for (int q3 = 0; q3 < 6; ++q3)
                *(float4*)(op + q3 * 4) = make_float4(
                    f[q3 * 4], f[q3 * 4 + 1], f[q3 * 4 + 2], f[q3 * 4 + 3]);
        }
    }
}

extern "C" void kernel_launch(void* const* d_in, const int* in_sizes, int n_in,
                              void* d_out, int out_size, void* d_ws, size_t ws_size,
                              hipStream_t stream) {
    const float* x    = (const float*)d_in[0];
    const float* sup  = (const float*)d_in[1];
    const float* W    = (const float*)d_in[2];
    const float* bias = (const float*)d_in[3];
    float* out = (float*)d_out;

    __hip_bfloat16* xTb  = (__hip_bfloat16*)d_ws;
    __hip_bfloat16* stpb = xTb + XTB_ELEMS;
    __hip_bfloat16* Wb   = stpb + STP_ELEMS;

    int build_total = (int)(STP_ELEMS + WB_ELEMS);
    build_tabs<<<(build_total + 255) / 256, 256, 0, stream>>>(sup, W, stpb, Wb);
    transpose_x<<<Bb * NKS, 256, 0, stream>>>(x, xTb);
    graphconv_main<<<Bb * NWT, 512, 0, stream>>>(xTb, stpb, Wb, bias, out);
}